// Round 6
// baseline (752.992 us; speedup 1.0000x reference)
//
#include <hip/hip_runtime.h>

typedef _Float16 half8 __attribute__((ext_vector_type(8)));
typedef _Float16 h4 __attribute__((ext_vector_type(4)));
typedef _Float16 h2 __attribute__((ext_vector_type(2)));
typedef float f32x4 __attribute__((ext_vector_type(4)));

__device__ __forceinline__ unsigned fkey(float f) {
  unsigned u = __float_as_uint(f);
  return (u & 0x80000000u) ? ~u : (u | 0x80000000u);
}
__device__ __forceinline__ float funkey(unsigned k) {
  unsigned u = (k & 0x80000000u) ? (k ^ 0x80000000u) : ~k;
  return __uint_as_float(u);
}

// ---------------- weight convert: fp32 KxNC -> f16 transposed NC x Kpad ----------------
struct WD { const float* src; _Float16* dst; int K, NC, Kpad, base; };
struct WDs { WD d[10]; int total; };

__global__ __launch_bounds__(256) void k_wconv(WDs w) {
  int idx = blockIdx.x * 256 + threadIdx.x;
  if (idx >= w.total) return;
#pragma unroll
  for (int i = 0; i < 10; ++i) {
    int rel = idx - w.d[i].base;
    int sz = w.d[i].NC * w.d[i].Kpad;
    if (rel >= 0 && rel < sz) {
      int n = rel / w.d[i].Kpad;
      int k = rel - n * w.d[i].Kpad;
      w.d[i].dst[rel] = (k < w.d[i].K) ? (_Float16)w.d[i].src[(size_t)k * w.d[i].NC + n]
                                       : (_Float16)0.f;
      return;
    }
  }
}

// ---------------- CSR build ----------------
__global__ __launch_bounds__(256) void k_count(const int* __restrict__ dst,
                                               int* __restrict__ counts, int E) {
  int e = blockIdx.x * 256 + threadIdx.x;
  if (e < E) atomicAdd(&counts[dst[e]], 1);
}

__global__ __launch_bounds__(256) void k_scan1(const int* __restrict__ counts,
                                               int* __restrict__ offsets,
                                               int* __restrict__ blockSums, int N) {
  __shared__ int sm[256];
  int tid = threadIdx.x;
  int gid = blockIdx.x * 256 + tid;
  int v = (gid < N) ? counts[gid] : 0;
  sm[tid] = v;
  __syncthreads();
  for (int off = 1; off < 256; off <<= 1) {
    int t = (tid >= off) ? sm[tid - off] : 0;
    __syncthreads();
    sm[tid] += t;
    __syncthreads();
  }
  if (gid < N) offsets[gid] = sm[tid] - v;
  if (tid == 255) blockSums[blockIdx.x] = sm[255];
}

__global__ __launch_bounds__(1024) void k_scan2(int* __restrict__ blockSums, int NB) {
  __shared__ int sm[1024];
  int tid = threadIdx.x;
  int v = (tid < NB) ? blockSums[tid] : 0;
  sm[tid] = v;
  __syncthreads();
  for (int off = 1; off < 1024; off <<= 1) {
    int t = (tid >= off) ? sm[tid - off] : 0;
    __syncthreads();
    sm[tid] += t;
    __syncthreads();
  }
  if (tid < NB) blockSums[tid] = sm[tid] - v;
}

__global__ __launch_bounds__(256) void k_scan3(const int* __restrict__ counts,
                                               int* __restrict__ offsets,
                                               const int* __restrict__ blockSums,
                                               int* __restrict__ fillpos,
                                               float* __restrict__ deginv, int N, int E) {
  int gid = blockIdx.x * 256 + threadIdx.x;
  if (gid < N) {
    int off = offsets[gid] + blockSums[gid >> 8];
    offsets[gid] = off;
    fillpos[gid] = off;
    deginv[gid] = 1.f / fmaxf((float)counts[gid], 1.f);
  }
  if (gid == 0) offsets[N] = E;
}

__global__ __launch_bounds__(256) void k_fill(const int* __restrict__ src,
                                              const int* __restrict__ dst,
                                              int* __restrict__ fillpos,
                                              int* __restrict__ esrc, int E) {
  int e = blockIdx.x * 256 + threadIdx.x;
  if (e < E) {
    int p = atomicAdd(&fillpos[dst[e]], 1);
    esrc[p] = src[e];
  }
}

// ---------------- in-register feature chunk builder (8 cols at c0, row r) ----------------
// Concatenated feature layout (224 cols, f16-equivalent):
//   0..138  node_feat[0..138]
//   139..142 type_emb[int(node_feat[139])][0..3]
//   143..174 op_emb[opcode[r]][0..31]
//   175..192 cfg[0..17]
//   193..223 zero pad
__device__ __forceinline__ half8 build_feat8(int r, int c0,
    const float* __restrict__ node_feat, const float* __restrict__ cfgf,
    const int* __restrict__ opcode, const float* __restrict__ op_emb,
    const float* __restrict__ type_emb) {
  const float* fr = node_feat + (size_t)r * 140;
  float v[8];
  if (c0 <= 128) {  // verbatim copy, cols 0..135 (fr 16B-aligned: 140%4==0)
    float4 a = *(const float4*)(fr + c0);
    float4 b = *(const float4*)(fr + c0 + 4);
    v[0] = a.x; v[1] = a.y; v[2] = a.z; v[3] = a.w;
    v[4] = b.x; v[5] = b.y; v[6] = b.z; v[7] = b.w;
  } else if (c0 == 136) {  // feat 136-138 | type 0-3 | op 0
    v[0] = fr[136]; v[1] = fr[137]; v[2] = fr[138];
    int ty = min(max((int)fr[139], 0), 7);
    const float* te = type_emb + ty * 4;
    v[3] = te[0]; v[4] = te[1]; v[5] = te[2]; v[6] = te[3];
    v[7] = op_emb[opcode[r] * 32 + 0];
  } else if (c0 < 168) {  // op cols 1..24
    const float* o = op_emb + opcode[r] * 32 + (c0 - 143);
#pragma unroll
    for (int j = 0; j < 8; ++j) v[j] = o[j];
  } else if (c0 == 168) {  // op 25..31 | cfg 0
    const float* o = op_emb + opcode[r] * 32;
#pragma unroll
    for (int j = 0; j < 7; ++j) v[j] = o[25 + j];
    v[7] = cfgf[(size_t)r * 18 + 0];
  } else if (c0 < 192) {  // cfg 1..16
    const float* c = cfgf + (size_t)r * 18 + (c0 - 175);
#pragma unroll
    for (int j = 0; j < 8; ++j) v[j] = c[j];
  } else if (c0 == 192) {  // cfg 17 | zeros
    v[0] = cfgf[(size_t)r * 18 + 17];
#pragma unroll
    for (int j = 1; j < 8; ++j) v[j] = 0.f;
  } else {  // pad cols 200..223
#pragma unroll
    for (int j = 0; j < 8; ++j) v[j] = 0.f;
  }
  half8 o;
#pragma unroll
  for (int j = 0; j < 8; ++j) o[j] = (_Float16)v[j];
  return o;
}

// ---------------- fused encode: relu(concat-features @ Wenc + b) -> X1 (N x 128) -------
// Two-phase: (1) 256 threads build the 64-row f16 feature tile into LDS with 7
// INDEPENDENT chunk-builds per thread (thread-parallel, loads pipeline — the r3-r5
// inline-build put 28 serialized exec-masked gather chains in each wave's k-loop,
// which was the 115 µs latency wall); (2) barrier, then RT=1 MFMA with A from LDS
// (pitch 232 f16 -> 464 B row stride -> 2-way bank aliasing, free) and B direct
// from global (57 KB, L1-hot). LDS 29.7 KB -> 5 blocks/CU.
__global__ __launch_bounds__(256) void k_mmF(
    const float* __restrict__ node_feat, const float* __restrict__ cfgf,
    const int* __restrict__ opcode, const float* __restrict__ op_emb,
    const float* __restrict__ type_emb,
    const _Float16* __restrict__ W0, const float* __restrict__ bias,
    _Float16* __restrict__ Out, int N) {
  constexpr int K0 = 224, NC = 128;
  constexpr int NT = NC / 16;
  constexpr int PITCH = 232;  // 224 + 8 f16 pad
  __shared__ _Float16 sA[64 * PITCH];

  const int base = blockIdx.x * 64;
  // ---- phase 1: stage 64 rows x 28 chunks (=1792 = 7*256) into LDS ----
#pragma unroll
  for (int it = 0; it < 7; ++it) {
    int chunk = it * 256 + threadIdx.x;
    int r = chunk / 28;
    int c0 = (chunk - r * 28) * 8;
    int rg = min(base + r, N - 1);  // clamp: sources are exactly N rows
    half8 v = build_feat8(rg, c0, node_feat, cfgf, opcode, op_emb, type_emb);
    *(half8*)(sA + r * PITCH + c0) = v;
  }
  __syncthreads();

  // ---- phase 2: GEMM, wave w owns rows base + w*16 .. +15 ----
  const int lane = threadIdx.x & 63, wave = threadIdx.x >> 6;
  const int quad = lane >> 4, l15 = lane & 15;
  const int rr = wave * 16 + l15;  // row within block tile
  const int r0 = base + wave * 16;

  f32x4 acc[NT];
#pragma unroll
  for (int t = 0; t < NT; ++t) acc[t] = (f32x4)0.f;

#pragma unroll
  for (int k = 0; k < K0; k += 32) {
    half8 a = *(const half8*)(sA + rr * PITCH + quad * 8 + k);
#pragma unroll
    for (int t = 0; t < NT; ++t) {
      half8 b = *(const half8*)(W0 + (size_t)(t * 16 + l15) * K0 + quad * 8 + k);
      acc[t] = __builtin_amdgcn_mfma_f32_16x16x32_f16(a, b, acc[t], 0, 0, 0);
    }
  }

#pragma unroll
  for (int t = 0; t < NT; ++t) {
    float bv = bias[t * 16 + l15];
    acc[t][0] = fmaxf(acc[t][0] + bv, 0.f);
    acc[t][1] = fmaxf(acc[t][1] + bv, 0.f);
    acc[t][2] = fmaxf(acc[t][2] + bv, 0.f);
    acc[t][3] = fmaxf(acc[t][3] + bv, 0.f);
  }
#pragma unroll
  for (int j = 0; j < 4; ++j) {
    int r = r0 + quad * 4 + j;
    if (r < N) {
#pragma unroll
      for (int t = 0; t < NT; ++t)
        Out[(size_t)r * NC + t * 16 + l15] = (_Float16)acc[t][j];
    }
  }
}

// ---------------- MFMA GEMM, B staged in LDS ----------------
// Out[r,:] = epi( A0[r]@W0 (+ A1[r]@W1) + bias ), A f16 row-major pitch K, W f16
// transposed (NC x K). MODE 0 = relu, 1 = row L2-normalize.
// 256 thr = 4 waves; 64 rows/wave (4 row-tiles), 256 rows/block.
template <int K0, int K1, int NC, int MODE>
__global__ __launch_bounds__(256) void k_mm(
    const _Float16* __restrict__ A0, const _Float16* __restrict__ W0,
    const _Float16* __restrict__ A1, const _Float16* __restrict__ W1,
    const float* __restrict__ bias, _Float16* __restrict__ Out, int N) {
  constexpr int NT = NC / 16;  // col tiles
  constexpr int RT = 4;        // row tiles per wave
  constexpr int KP0 = K0 + 8;  // padded LDS pitch (f16)
  constexpr int KP1 = K1 + 8;
  __shared__ _Float16 sB0[NC * KP0];
  __shared__ _Float16 sB1[(K1 > 0) ? (NC * KP1) : 8];

  for (int idx = threadIdx.x; idx < NC * (K0 / 8); idx += 256) {
    int nn = idx / (K0 / 8), k8 = idx - nn * (K0 / 8);
    *(half8*)(sB0 + nn * KP0 + k8 * 8) = *(const half8*)(W0 + (size_t)nn * K0 + k8 * 8);
  }
  if constexpr (K1 > 0) {
    for (int idx = threadIdx.x; idx < NC * (K1 / 8); idx += 256) {
      int nn = idx / (K1 / 8), k8 = idx - nn * (K1 / 8);
      *(half8*)(sB1 + nn * KP1 + k8 * 8) = *(const half8*)(W1 + (size_t)nn * K1 + k8 * 8);
    }
  }
  __syncthreads();

  const int lane = threadIdx.x & 63, wave = threadIdx.x >> 6;
  const int quad = lane >> 4, l15 = lane & 15;
  const int r0 = blockIdx.x * 256 + wave * 64;

  f32x4 acc[RT][NT];
#pragma unroll
  for (int rt = 0; rt < RT; ++rt)
#pragma unroll
    for (int t = 0; t < NT; ++t) acc[rt][t] = (f32x4)0.f;

  {
    const _Float16* ap = A0 + (size_t)(r0 + l15) * K0 + quad * 8;
#pragma unroll
    for (int k = 0; k < K0; k += 32) {
      half8 a[RT];
#pragma unroll
      for (int rt = 0; rt < RT; ++rt) a[rt] = *(const half8*)(ap + (size_t)rt * 16 * K0 + k);
#pragma unroll
      for (int t = 0; t < NT; ++t) {
        half8 b = *(const half8*)(sB0 + (t * 16 + l15) * KP0 + quad * 8 + k);
#pragma unroll
        for (int rt = 0; rt < RT; ++rt)
          acc[rt][t] = __builtin_amdgcn_mfma_f32_16x16x32_f16(a[rt], b, acc[rt][t], 0, 0, 0);
      }
    }
  }
  if constexpr (K1 > 0) {
    const _Float16* ap = A1 + (size_t)(r0 + l15) * K1 + quad * 8;
#pragma unroll
    for (int k = 0; k < K1; k += 32) {
      half8 a[RT];
#pragma unroll
      for (int rt = 0; rt < RT; ++rt) a[rt] = *(const half8*)(ap + (size_t)rt * 16 * K1 + k);
#pragma unroll
      for (int t = 0; t < NT; ++t) {
        half8 b = *(const half8*)(sB1 + (t * 16 + l15) * KP1 + quad * 8 + k);
#pragma unroll
        for (int rt = 0; rt < RT; ++rt)
          acc[rt][t] = __builtin_amdgcn_mfma_f32_16x16x32_f16(a[rt], b, acc[rt][t], 0, 0, 0);
      }
    }
  }

#pragma unroll
  for (int rt = 0; rt < RT; ++rt) {
#pragma unroll
    for (int t = 0; t < NT; ++t) {
      float bv = bias[t * 16 + l15];
      acc[rt][t][0] += bv; acc[rt][t][1] += bv;
      acc[rt][t][2] += bv; acc[rt][t][3] += bv;
    }
    if constexpr (MODE == 1) {
      f32x4 ss = (f32x4)0.f;
#pragma unroll
      for (int t = 0; t < NT; ++t) ss += acc[rt][t] * acc[rt][t];
#pragma unroll
      for (int j = 0; j < 4; ++j) {
        float s = ss[j];
        s += __shfl_xor(s, 1);
        s += __shfl_xor(s, 2);
        s += __shfl_xor(s, 4);
        s += __shfl_xor(s, 8);
        float sc = 1.f / fmaxf(sqrtf(s), 1e-12f);
#pragma unroll
        for (int t = 0; t < NT; ++t) acc[rt][t][j] *= sc;
      }
    } else {
#pragma unroll
      for (int t = 0; t < NT; ++t) {
        acc[rt][t][0] = fmaxf(acc[rt][t][0], 0.f);
        acc[rt][t][1] = fmaxf(acc[rt][t][1], 0.f);
        acc[rt][t][2] = fmaxf(acc[rt][t][2], 0.f);
        acc[rt][t][3] = fmaxf(acc[rt][t][3], 0.f);
      }
    }
#pragma unroll
    for (int j = 0; j < 4; ++j) {
      int r = r0 + rt * 16 + quad * 4 + j;
      if (r < N) {
#pragma unroll
        for (int t = 0; t < NT; ++t)
          Out[(size_t)r * NC + t * 16 + l15] = (_Float16)acc[rt][t][j];
      }
    }
  }
}

// ---------------- CSR mean aggregation (f16, fp32 acc), 8B/lane + 4x edge unroll ----
template <int NC>
__global__ __launch_bounds__(256) void k_agg(const _Float16* __restrict__ xp,
                                             const int* __restrict__ offs,
                                             const int* __restrict__ esrc,
                                             const float* __restrict__ deginv,
                                             _Float16* __restrict__ agg, int N) {
  constexpr int LPN = NC / 4;  // lanes per node, 4 f16 (8B) per lane
  int t = blockIdx.x * 256 + threadIdx.x;
  int node = t / LPN;
  int lane = t - node * LPN;
  if (node >= N) return;
  int s0 = offs[node], s1 = offs[node + 1];
  float a0 = 0.f, a1 = 0.f, a2 = 0.f, a3 = 0.f;
  for (int i = s0; i < s1; i += 4) {
    int nlast = s1 - 1;
    int e0 = esrc[i];
    int e1 = esrc[min(i + 1, nlast)];
    int e2 = esrc[min(i + 2, nlast)];
    int e3 = esrc[min(i + 3, nlast)];
    h4 v0 = ((const h4*)(xp + (size_t)e0 * NC))[lane];
    h4 v1 = ((const h4*)(xp + (size_t)e1 * NC))[lane];
    h4 v2 = ((const h4*)(xp + (size_t)e2 * NC))[lane];
    h4 v3 = ((const h4*)(xp + (size_t)e3 * NC))[lane];
    a0 += (float)v0[0]; a1 += (float)v0[1]; a2 += (float)v0[2]; a3 += (float)v0[3];
    if (i + 1 < s1) { a0 += (float)v1[0]; a1 += (float)v1[1]; a2 += (float)v1[2]; a3 += (float)v1[3]; }
    if (i + 2 < s1) { a0 += (float)v2[0]; a1 += (float)v2[1]; a2 += (float)v2[2]; a3 += (float)v2[3]; }
    if (i + 3 < s1) { a0 += (float)v3[0]; a1 += (float)v3[1]; a2 += (float)v3[2]; a3 += (float)v3[3]; }
  }
  float di = deginv[node];
  h4 o;
  o[0] = (_Float16)(a0 * di); o[1] = (_Float16)(a1 * di);
  o[2] = (_Float16)(a2 * di); o[3] = (_Float16)(a3 * di);
  ((h4*)(agg + (size_t)node * NC))[lane] = o;
}

// ---------------- pooling ----------------
__global__ __launch_bounds__(256) void k_pool1(const _Float16* __restrict__ x,
                                               const int* __restrict__ batch,
                                               unsigned* __restrict__ gkey,
                                               float* __restrict__ gsum,
                                               int* __restrict__ gcnt, int N) {
  int chunk = blockIdx.x * 4 + (threadIdx.x >> 6);
  int lane = threadIdx.x & 63;
  int n0 = chunk * 64;
  if (n0 >= N) return;
  int n1 = min(n0 + 64, N);
  float rmax = -3.4e38f, rsum = 0.f;
  int rcnt = 0, curb = batch[n0];
  for (int n = n0; n < n1; ++n) {
    int b = batch[n];
    if (b != curb) {
      atomicMax(&gkey[curb * 64 + lane], fkey(rmax));
      atomicAdd(&gsum[curb * 64 + lane], rsum);
      if (lane == 0) atomicAdd(&gcnt[curb], rcnt);
      rmax = -3.4e38f; rsum = 0.f; rcnt = 0; curb = b;
    }
    float v = (float)x[(size_t)n * 64 + lane];
    rmax = fmaxf(rmax, v);
    rsum += v;
    rcnt++;
  }
  atomicMax(&gkey[curb * 64 + lane], fkey(rmax));
  atomicAdd(&gsum[curb * 64 + lane], rsum);
  if (lane == 0) atomicAdd(&gcnt[curb], rcnt);
}

__global__ __launch_bounds__(1024) void k_pool2(const unsigned* __restrict__ gkey,
                                                const float* __restrict__ gsum,
                                                const int* __restrict__ gcnt,
                                                const float* __restrict__ post_w,
                                                const float* __restrict__ post_b,
                                                float* __restrict__ out) {
  int b = threadIdx.x >> 6, lane = threadIdx.x & 63;
  float m = funkey(gkey[b * 64 + lane]);
  float s = gsum[b * 64 + lane];
  float c = (float)gcnt[b];
  float g = m + s / fmaxf(c, 1.f);
  float ss = g * g;
#pragma unroll
  for (int off = 1; off < 64; off <<= 1) ss += __shfl_xor(ss, off);
  float gn = g / fmaxf(sqrtf(ss), 1e-30f);
  float contrib = gn * post_w[lane];
#pragma unroll
  for (int off = 1; off < 64; off <<= 1) contrib += __shfl_xor(contrib, off);
  if (lane == 0) out[b] = contrib + post_b[0];
}

extern "C" void kernel_launch(void* const* d_in, const int* in_sizes, int n_in,
                              void* d_out, int out_size, void* d_ws, size_t ws_size,
                              hipStream_t stream) {
  const float* node_feat = (const float*)d_in[0];
  const float* cfgf      = (const float*)d_in[1];
  const int*   opcode    = (const int*)d_in[2];
  const int*   eidx      = (const int*)d_in[3];
  const int*   batch     = (const int*)d_in[4];
  const float* op_emb    = (const float*)d_in[5];
  const float* type_emb  = (const float*)d_in[6];
  const float* lin_w     = (const float*)d_in[7];
  const float* lin_b     = (const float*)d_in[8];
  const float* post_w    = (const float*)d_in[9];
  const float* post_b    = (const float*)d_in[10];
  const float* wp[3] = {(const float*)d_in[11], (const float*)d_in[16], (const float*)d_in[21]};
  const float* bp[3] = {(const float*)d_in[12], (const float*)d_in[17], (const float*)d_in[22]};
  const float* wl[3] = {(const float*)d_in[13], (const float*)d_in[18], (const float*)d_in[23]};
  const float* bl[3] = {(const float*)d_in[14], (const float*)d_in[19], (const float*)d_in[24]};
  const float* wr[3] = {(const float*)d_in[15], (const float*)d_in[20], (const float*)d_in[25]};

  const int N = in_sizes[2];
  const int E = in_sizes[3] / 2;
  const int NPAD = ((N + 255) / 256) * 256;
  const int* e_src = eidx;
  const int* e_dst = eidx + E;

  char* p = (char*)d_ws;
  auto alloc = [&](size_t bytes) -> void* {
    void* r = (void*)p;
    p += (bytes + 255) & ~(size_t)255;
    return r;
  };
  _Float16* X1 = (_Float16*)alloc((size_t)NPAD * 128 * 2);
  _Float16* R2 = (_Float16*)alloc((size_t)NPAD * 128 * 2);
  _Float16* R3 = (_Float16*)alloc((size_t)NPAD * 128 * 2);
  _Float16* WT = (_Float16*)alloc(86016 * 2);
  int* counts    = (int*)alloc((size_t)N * 4);
  int* offsets   = (int*)alloc((size_t)(N + 1) * 4);
  int* fillpos   = (int*)alloc((size_t)N * 4);
  float* deginv  = (float*)alloc((size_t)N * 4);
  int* blockSums = (int*)alloc(1024 * 4);
  int* esrc      = (int*)alloc((size_t)E * 4);
  unsigned* gkey = (unsigned*)alloc(16 * 64 * 4);
  float* gsum    = (float*)alloc(16 * 64 * 4);
  int* gcnt      = (int*)alloc(16 * 4);
  (void)ws_size; (void)n_in; (void)out_size;

  _Float16* WTenc = WT + 0;       // 128 x 224
  _Float16* WTp0  = WT + 28672;   // 128 x 128
  _Float16* WTl0  = WT + 45056;   // 64 x 128
  _Float16* WTr0  = WT + 53248;   // 64 x 128
  _Float16* WTp1  = WT + 61440;   // 64 x 64
  _Float16* WTl1  = WT + 65536;
  _Float16* WTr1  = WT + 69632;
  _Float16* WTp2  = WT + 73728;
  _Float16* WTl2  = WT + 77824;
  _Float16* WTr2  = WT + 81920;

  WDs wds;
  wds.d[0] = {lin_w, WTenc, 193, 128, 224, 0};
  wds.d[1] = {wp[0], WTp0, 128, 128, 128, 28672};
  wds.d[2] = {wl[0], WTl0, 128, 64, 128, 45056};
  wds.d[3] = {wr[0], WTr0, 128, 64, 128, 53248};
  wds.d[4] = {wp[1], WTp1, 64, 64, 64, 61440};
  wds.d[5] = {wl[1], WTl1, 64, 64, 64, 65536};
  wds.d[6] = {wr[1], WTr1, 64, 64, 64, 69632};
  wds.d[7] = {wp[2], WTp2, 64, 64, 64, 73728};
  wds.d[8] = {wl[2], WTl2, 64, 64, 64, 77824};
  wds.d[9] = {wr[2], WTr2, 64, 64, 64, 81920};
  wds.total = 86016;

  hipMemsetAsync(counts, 0, (size_t)N * 4, stream);
  hipMemsetAsync(gkey, 0, 16 * 64 * 4, stream);
  hipMemsetAsync(gsum, 0, 16 * 64 * 4, stream);
  hipMemsetAsync(gcnt, 0, 16 * 4, stream);
  // Zero the never-stored tail rows [N, NPAD) of the activation buffers so every
  // byte any kernel reads is written in-launch -> output is call-invariant under
  // graph replay / workspace re-poisoning (k_mm A-loads cover NPAD rows; stores
  // are guarded r < N). 48 KiB each — negligible.
  if (NPAD > N) {
    const size_t tail = (size_t)(NPAD - N) * 128 * 2;
    hipMemsetAsync(X1 + (size_t)N * 128, 0, tail, stream);
    hipMemsetAsync(R2 + (size_t)N * 128, 0, tail, stream);
    hipMemsetAsync(R3 + (size_t)N * 128, 0, tail, stream);
  }

  const int nbE = (E + 255) / 256;
  const int nbN = (N + 255) / 256;
  const int nbMM = NPAD / 256;
  const int nbMMF = NPAD / 64;
  const int nbA128 = ((size_t)N * 32 + 255) / 256;
  const int nbA64  = ((size_t)N * 16 + 255) / 256;
  const int nbP = ((N + 63) / 64 + 3) / 4;

  k_wconv<<<(86016 + 255) / 256, 256, 0, stream>>>(wds);
  k_count<<<nbE, 256, 0, stream>>>(e_dst, counts, E);
  k_scan1<<<nbN, 256, 0, stream>>>(counts, offsets, blockSums, N);
  k_scan2<<<1, 1024, 0, stream>>>(blockSums, nbN);
  k_scan3<<<nbN, 256, 0, stream>>>(counts, offsets, blockSums, fillpos, deginv, N, E);
  k_fill<<<nbE, 256, 0, stream>>>(e_src, e_dst, fillpos, esrc, E);

  // fused encode: relu(concat @ Wenc + lin_b) -> X1 (N x 128), no F intermediate
  k_mmF<<<nbMMF, 256, 0, stream>>>(node_feat, cfgf, opcode, op_emb, type_emb,
                                   WTenc, lin_b, X1, N);

  // ---- layer 0 ----
  k_mm<128, 0, 128, 0><<<nbMM, 256, 0, stream>>>(X1, WTp0, nullptr, nullptr, bp[0], R2, N);
  k_agg<128><<<nbA128, 256, 0, stream>>>(R2, offsets, esrc, deginv, R3, N);
  k_mm<128, 128, 64, 1><<<nbMM, 256, 0, stream>>>(R3, WTl0, X1, WTr0, bl[0], R2, N);
  // ---- layer 1 ----
  k_mm<64, 0, 64, 0><<<nbMM, 256, 0, stream>>>(R2, WTp1, nullptr, nullptr, bp[1], R3, N);
  k_agg<64><<<nbA64, 256, 0, stream>>>(R3, offsets, esrc, deginv, X1, N);
  k_mm<64, 64, 64, 1><<<nbMM, 256, 0, stream>>>(X1, WTl1, R2, WTr1, bl[1], R3, N);
  // ---- layer 2 ----
  k_mm<64, 0, 64, 0><<<nbMM, 256, 0, stream>>>(R3, WTp2, nullptr, nullptr, bp[2], X1, N);
  k_agg<64><<<nbA64, 256, 0, stream>>>(X1, offsets, esrc, deginv, R2, N);
  k_mm<64, 64, 64, 1><<<nbMM, 256, 0, stream>>>(R2, WTl2, R3, WTr2, bl[2], X1, N);

  // pooling -> out (B=16)
  k_pool1<<<nbP, 256, 0, stream>>>(X1, batch, gkey, gsum, gcnt, N);
  k_pool2<<<1, 1024, 0, stream>>>(gkey, gsum, gcnt, post_w, post_b, (float*)d_out);
}

// Round 7
// 688.425 us; speedup vs baseline: 1.0938x; 1.0938x over previous
//
#include <hip/hip_runtime.h>

typedef _Float16 half8 __attribute__((ext_vector_type(8)));
typedef _Float16 h4 __attribute__((ext_vector_type(4)));
typedef _Float16 h2 __attribute__((ext_vector_type(2)));
typedef float f32x4 __attribute__((ext_vector_type(4)));

__device__ __forceinline__ unsigned fkey(float f) {
  unsigned u = __float_as_uint(f);
  return (u & 0x80000000u) ? ~u : (u | 0x80000000u);
}
__device__ __forceinline__ float funkey(unsigned k) {
  unsigned u = (k & 0x80000000u) ? (k ^ 0x80000000u) : ~k;
  return __uint_as_float(u);
}

__device__ __forceinline__ half8 cvt8(float4 a, float4 b) {
  half8 o;
  o[0] = (_Float16)a.x; o[1] = (_Float16)a.y; o[2] = (_Float16)a.z; o[3] = (_Float16)a.w;
  o[4] = (_Float16)b.x; o[5] = (_Float16)b.y; o[6] = (_Float16)b.z; o[7] = (_Float16)b.w;
  return o;
}

// ---------------- weight convert: fp32 KxNC -> f16 transposed NC x Kpad ----------------
struct WD { const float* src; _Float16* dst; int K, NC, Kpad, base; };
struct WDs { WD d[10]; int total; };

__global__ __launch_bounds__(256) void k_wconv(WDs w) {
  int idx = blockIdx.x * 256 + threadIdx.x;
  if (idx >= w.total) return;
#pragma unroll
  for (int i = 0; i < 10; ++i) {
    int rel = idx - w.d[i].base;
    int sz = w.d[i].NC * w.d[i].Kpad;
    if (rel >= 0 && rel < sz) {
      int n = rel / w.d[i].Kpad;
      int k = rel - n * w.d[i].Kpad;
      w.d[i].dst[rel] = (k < w.d[i].K) ? (_Float16)w.d[i].src[(size_t)k * w.d[i].NC + n]
                                       : (_Float16)0.f;
      return;
    }
  }
}

// ---------------- CSR build ----------------
__global__ __launch_bounds__(256) void k_count(const int* __restrict__ dst,
                                               int* __restrict__ counts, int E) {
  int e = blockIdx.x * 256 + threadIdx.x;
  if (e < E) atomicAdd(&counts[dst[e]], 1);
}

__global__ __launch_bounds__(256) void k_scan1(const int* __restrict__ counts,
                                               int* __restrict__ offsets,
                                               int* __restrict__ blockSums, int N) {
  __shared__ int sm[256];
  int tid = threadIdx.x;
  int gid = blockIdx.x * 256 + tid;
  int v = (gid < N) ? counts[gid] : 0;
  sm[tid] = v;
  __syncthreads();
  for (int off = 1; off < 256; off <<= 1) {
    int t = (tid >= off) ? sm[tid - off] : 0;
    __syncthreads();
    sm[tid] += t;
    __syncthreads();
  }
  if (gid < N) offsets[gid] = sm[tid] - v;
  if (tid == 255) blockSums[blockIdx.x] = sm[255];
}

__global__ __launch_bounds__(1024) void k_scan2(int* __restrict__ blockSums, int NB) {
  __shared__ int sm[1024];
  int tid = threadIdx.x;
  int v = (tid < NB) ? blockSums[tid] : 0;
  sm[tid] = v;
  __syncthreads();
  for (int off = 1; off < 1024; off <<= 1) {
    int t = (tid >= off) ? sm[tid - off] : 0;
    __syncthreads();
    sm[tid] += t;
    __syncthreads();
  }
  if (tid < NB) blockSums[tid] = sm[tid] - v;
}

__global__ __launch_bounds__(256) void k_scan3(const int* __restrict__ counts,
                                               int* __restrict__ offsets,
                                               const int* __restrict__ blockSums,
                                               int* __restrict__ fillpos,
                                               float* __restrict__ deginv, int N, int E) {
  int gid = blockIdx.x * 256 + threadIdx.x;
  if (gid < N) {
    int off = offsets[gid] + blockSums[gid >> 8];
    offsets[gid] = off;
    fillpos[gid] = off;
    deginv[gid] = 1.f / fmaxf((float)counts[gid], 1.f);
  }
  if (gid == 0) offsets[N] = E;
}

__global__ __launch_bounds__(256) void k_fill(const int* __restrict__ src,
                                              const int* __restrict__ dst,
                                              int* __restrict__ fillpos,
                                              int* __restrict__ esrc, int E) {
  int e = blockIdx.x * 256 + threadIdx.x;
  if (e < E) {
    int p = atomicAdd(&fillpos[dst[e]], 1);
    esrc[p] = src[e];
  }
}

// ---------------- fused encode: relu(concat-features @ Wenc + b) -> X1 (N x 128) -------
// RT=1, one row per thread across all 7 k-steps. ALL global loads are issued at kernel
// start with branchlessly-selected ALIGNED addresses (2 dependency layers: opcode/f136
// first, op_emb/type_emb rows second); the 7 A-fragments are then assembled with
// register-only selects, so the divergent steps 4-6 contain no loads. This removes the
// 7-serialized-gather-chain stall that capped r3-r6 at 115-177 µs.
// Virtual feature layout (224 cols): 0..138 nf | 139..142 type_emb[nf139] |
// 143..174 op_emb[opcode] | 175..192 cfg | 193..223 zeros.
__global__ __launch_bounds__(256) void k_mmF(
    const float* __restrict__ node_feat, const float* __restrict__ cfgf,
    const int* __restrict__ opcode, const float* __restrict__ op_emb,
    const float* __restrict__ type_emb,
    const _Float16* __restrict__ W0, const float* __restrict__ bias,
    _Float16* __restrict__ Out, int N) {
  constexpr int K0 = 224, NC = 128;
  constexpr int NT = NC / 16;

  const int lane = threadIdx.x & 63, wave = threadIdx.x >> 6;
  const int quad = lane >> 4, l15 = lane & 15;
  const int r0 = blockIdx.x * 64 + wave * 16;
  const int r = min(r0 + l15, N - 1);  // clamp: sources are exactly N rows
  const float* fr = node_feat + (size_t)r * 140;
  const float* cg = cfgf + (size_t)r * 18;

  // ---- layer-0 loads (independent) ----
  int opc = opcode[r];
  float4 f136 = *(const float4*)(fr + 136);            // cols 136..139 (139 = type id)
  float4 fA0 = *(const float4*)(fr + quad * 8 + 0),  fB0 = *(const float4*)(fr + quad * 8 + 4);
  float4 fA1 = *(const float4*)(fr + quad * 8 + 32), fB1 = *(const float4*)(fr + quad * 8 + 36);
  float4 fA2 = *(const float4*)(fr + quad * 8 + 64), fB2 = *(const float4*)(fr + quad * 8 + 68);
  float4 fA3 = *(const float4*)(fr + quad * 8 + 96), fB3 = *(const float4*)(fr + quad * 8 + 100);
  float4 fXa = *(const float4*)(fr + 128),           fXb = *(const float4*)(fr + 132);
  float c17 = cg[17];
  const int cshift = (quad == 3) ? 8 : 0;              // q3 reads cfg[8..17], others cfg[0..9]
  float2 c2a = *(const float2*)(cg + cshift + 0);
  float2 c2b = *(const float2*)(cg + cshift + 2);
  float2 c2c = *(const float2*)(cg + cshift + 4);
  float2 c2d = *(const float2*)(cg + cshift + 6);
  float2 c2e = *(const float2*)(cg + cshift + 8);

  // ---- layer-1 loads (1 dependency hop) ----
  const float* ob = op_emb + opc * 32;
  // per-quad op span starts: q0->17..24, q1->25..31, q2->1..8, q3->9..16 (all = 1 mod 4)
  const int opoff = (quad == 0) ? 17 : (quad == 1) ? 25 : (quad == 2) ? 1 : 9;
  float4 oA = *(const float4*)(ob + opoff - 1);        // aligned slot containing start
  float4 oB = *(const float4*)(ob + opoff + 3);
  float4 oC4 = *(const float4*)(ob + min(opoff + 7, 28));  // clamp keeps q1 in-bounds
  float opC = ob[0];
  int ty = min(max((int)f136.w, 0), 7);
  float4 tyv = *(const float4*)(type_emb + ty * 4);

  // ---- register-only fragment assembly ----
  half8 a0 = cvt8(fA0, fB0), a1 = cvt8(fA1, fB1), a2 = cvt8(fA2, fB2), a3 = cvt8(fA3, fB3);
  half8 opH;  // op_emb[opoff .. opoff+7]
  opH[0] = (_Float16)oA.y; opH[1] = (_Float16)oA.z; opH[2] = (_Float16)oA.w;
  opH[3] = (_Float16)oB.x; opH[4] = (_Float16)oB.y; opH[5] = (_Float16)oB.z;
  opH[6] = (_Float16)oB.w; opH[7] = (_Float16)oC4.x;
  half8 cfH;  // cfg[cshift+1 .. cshift+8]
  cfH[0] = (_Float16)c2a.y; cfH[1] = (_Float16)c2b.x; cfH[2] = (_Float16)c2b.y;
  cfH[3] = (_Float16)c2c.x; cfH[4] = (_Float16)c2c.y; cfH[5] = (_Float16)c2d.x;
  cfH[6] = (_Float16)c2d.y; cfH[7] = (_Float16)c2e.x;
  half8 z8;
#pragma unroll
  for (int j = 0; j < 8; ++j) z8[j] = (_Float16)0.f;

  half8 a4, a5, a6;
  if (quad == 0) {           // k4: cols 128..135 | k5: op 17..24 | k6: cfg17 + zeros
    a4 = cvt8(fXa, fXb);
    a5 = opH;
    a6 = z8; a6[0] = (_Float16)c17;
  } else if (quad == 1) {    // k4: nf136-138|type0-3|op0 | k5: op25-31|cfg0 | k6: zeros
    a4[0] = (_Float16)f136.x; a4[1] = (_Float16)f136.y; a4[2] = (_Float16)f136.z;
    a4[3] = (_Float16)tyv.x;  a4[4] = (_Float16)tyv.y;  a4[5] = (_Float16)tyv.z;
    a4[6] = (_Float16)tyv.w;  a4[7] = (_Float16)opC;
    a5 = opH; a5[7] = (_Float16)c2a.x;
    a6 = z8;
  } else {                   // q2: op1-8 / cfg1-8 ; q3: op9-16 / cfg9-16 ; zeros
    a4 = opH;
    a5 = cfH;
    a6 = z8;
  }

  f32x4 acc[NT];
#pragma unroll
  for (int t = 0; t < NT; ++t) acc[t] = (f32x4)0.f;

  const half8 A[7] = {a0, a1, a2, a3, a4, a5, a6};
#pragma unroll
  for (int k = 0; k < 7; ++k) {
#pragma unroll
    for (int t = 0; t < NT; ++t) {
      half8 b = *(const half8*)(W0 + (size_t)(t * 16 + l15) * K0 + quad * 8 + k * 32);
      acc[t] = __builtin_amdgcn_mfma_f32_16x16x32_f16(A[k], b, acc[t], 0, 0, 0);
    }
  }

#pragma unroll
  for (int t = 0; t < NT; ++t) {
    float bv = bias[t * 16 + l15];
    acc[t][0] = fmaxf(acc[t][0] + bv, 0.f);
    acc[t][1] = fmaxf(acc[t][1] + bv, 0.f);
    acc[t][2] = fmaxf(acc[t][2] + bv, 0.f);
    acc[t][3] = fmaxf(acc[t][3] + bv, 0.f);
  }
#pragma unroll
  for (int j = 0; j < 4; ++j) {
    int rw = r0 + quad * 4 + j;
    if (rw < N) {
#pragma unroll
      for (int t = 0; t < NT; ++t)
        Out[(size_t)rw * NC + t * 16 + l15] = (_Float16)acc[t][j];
    }
  }
}

// ---------------- MFMA GEMM, B staged in LDS ----------------
// Out[r,:] = epi( A0[r]@W0 (+ A1[r]@W1) + bias ), A f16 row-major pitch K, W f16
// transposed (NC x K). MODE 0 = relu, 1 = row L2-normalize.
// 256 thr = 4 waves; 64 rows/wave (4 row-tiles), 256 rows/block.
template <int K0, int K1, int NC, int MODE>
__global__ __launch_bounds__(256) void k_mm(
    const _Float16* __restrict__ A0, const _Float16* __restrict__ W0,
    const _Float16* __restrict__ A1, const _Float16* __restrict__ W1,
    const float* __restrict__ bias, _Float16* __restrict__ Out, int N) {
  constexpr int NT = NC / 16;  // col tiles
  constexpr int RT = 4;        // row tiles per wave
  constexpr int KP0 = K0 + 8;  // padded LDS pitch (f16)
  constexpr int KP1 = K1 + 8;
  __shared__ _Float16 sB0[NC * KP0];
  __shared__ _Float16 sB1[(K1 > 0) ? (NC * KP1) : 8];

  for (int idx = threadIdx.x; idx < NC * (K0 / 8); idx += 256) {
    int nn = idx / (K0 / 8), k8 = idx - nn * (K0 / 8);
    *(half8*)(sB0 + nn * KP0 + k8 * 8) = *(const half8*)(W0 + (size_t)nn * K0 + k8 * 8);
  }
  if constexpr (K1 > 0) {
    for (int idx = threadIdx.x; idx < NC * (K1 / 8); idx += 256) {
      int nn = idx / (K1 / 8), k8 = idx - nn * (K1 / 8);
      *(half8*)(sB1 + nn * KP1 + k8 * 8) = *(const half8*)(W1 + (size_t)nn * K1 + k8 * 8);
    }
  }
  __syncthreads();

  const int lane = threadIdx.x & 63, wave = threadIdx.x >> 6;
  const int quad = lane >> 4, l15 = lane & 15;
  const int r0 = blockIdx.x * 256 + wave * 64;

  f32x4 acc[RT][NT];
#pragma unroll
  for (int rt = 0; rt < RT; ++rt)
#pragma unroll
    for (int t = 0; t < NT; ++t) acc[rt][t] = (f32x4)0.f;

  {
    const _Float16* ap = A0 + (size_t)(r0 + l15) * K0 + quad * 8;
#pragma unroll
    for (int k = 0; k < K0; k += 32) {
      half8 a[RT];
#pragma unroll
      for (int rt = 0; rt < RT; ++rt) a[rt] = *(const half8*)(ap + (size_t)rt * 16 * K0 + k);
#pragma unroll
      for (int t = 0; t < NT; ++t) {
        half8 b = *(const half8*)(sB0 + (t * 16 + l15) * KP0 + quad * 8 + k);
#pragma unroll
        for (int rt = 0; rt < RT; ++rt)
          acc[rt][t] = __builtin_amdgcn_mfma_f32_16x16x32_f16(a[rt], b, acc[rt][t], 0, 0, 0);
      }
    }
  }
  if constexpr (K1 > 0) {
    const _Float16* ap = A1 + (size_t)(r0 + l15) * K1 + quad * 8;
#pragma unroll
    for (int k = 0; k < K1; k += 32) {
      half8 a[RT];
#pragma unroll
      for (int rt = 0; rt < RT; ++rt) a[rt] = *(const half8*)(ap + (size_t)rt * 16 * K1 + k);
#pragma unroll
      for (int t = 0; t < NT; ++t) {
        half8 b = *(const half8*)(sB1 + (t * 16 + l15) * KP1 + quad * 8 + k);
#pragma unroll
        for (int rt = 0; rt < RT; ++rt)
          acc[rt][t] = __builtin_amdgcn_mfma_f32_16x16x32_f16(a[rt], b, acc[rt][t], 0, 0, 0);
      }
    }
  }

#pragma unroll
  for (int rt = 0; rt < RT; ++rt) {
#pragma unroll
    for (int t = 0; t < NT; ++t) {
      float bv = bias[t * 16 + l15];
      acc[rt][t][0] += bv; acc[rt][t][1] += bv;
      acc[rt][t][2] += bv; acc[rt][t][3] += bv;
    }
    if constexpr (MODE == 1) {
      f32x4 ss = (f32x4)0.f;
#pragma unroll
      for (int t = 0; t < NT; ++t) ss += acc[rt][t] * acc[rt][t];
#pragma unroll
      for (int j = 0; j < 4; ++j) {
        float s = ss[j];
        s += __shfl_xor(s, 1);
        s += __shfl_xor(s, 2);
        s += __shfl_xor(s, 4);
        s += __shfl_xor(s, 8);
        float sc = 1.f / fmaxf(sqrtf(s), 1e-12f);
#pragma unroll
        for (int t = 0; t < NT; ++t) acc[rt][t][j] *= sc;
      }
    } else {
#pragma unroll
      for (int t = 0; t < NT; ++t) {
        acc[rt][t][0] = fmaxf(acc[rt][t][0], 0.f);
        acc[rt][t][1] = fmaxf(acc[rt][t][1], 0.f);
        acc[rt][t][2] = fmaxf(acc[rt][t][2], 0.f);
        acc[rt][t][3] = fmaxf(acc[rt][t][3], 0.f);
      }
    }
#pragma unroll
    for (int j = 0; j < 4; ++j) {
      int r = r0 + rt * 16 + quad * 4 + j;
      if (r < N) {
#pragma unroll
        for (int t = 0; t < NT; ++t)
          Out[(size_t)r * NC + t * 16 + l15] = (_Float16)acc[rt][t][j];
      }
    }
  }
}

// ---------------- CSR mean aggregation (f16, fp32 acc), 8B/lane + 4x edge unroll ----
template <int NC>
__global__ __launch_bounds__(256) void k_agg(const _Float16* __restrict__ xp,
                                             const int* __restrict__ offs,
                                             const int* __restrict__ esrc,
                                             const float* __restrict__ deginv,
                                             _Float16* __restrict__ agg, int N) {
  constexpr int LPN = NC / 4;  // lanes per node, 4 f16 (8B) per lane
  int t = blockIdx.x * 256 + threadIdx.x;
  int node = t / LPN;
  int lane = t - node * LPN;
  if (node >= N) return;
  int s0 = offs[node], s1 = offs[node + 1];
  float a0 = 0.f, a1 = 0.f, a2 = 0.f, a3 = 0.f;
  for (int i = s0; i < s1; i += 4) {
    int nlast = s1 - 1;
    int e0 = esrc[i];
    int e1 = esrc[min(i + 1, nlast)];
    int e2 = esrc[min(i + 2, nlast)];
    int e3 = esrc[min(i + 3, nlast)];
    h4 v0 = ((const h4*)(xp + (size_t)e0 * NC))[lane];
    h4 v1 = ((const h4*)(xp + (size_t)e1 * NC))[lane];
    h4 v2 = ((const h4*)(xp + (size_t)e2 * NC))[lane];
    h4 v3 = ((const h4*)(xp + (size_t)e3 * NC))[lane];
    a0 += (float)v0[0]; a1 += (float)v0[1]; a2 += (float)v0[2]; a3 += (float)v0[3];
    if (i + 1 < s1) { a0 += (float)v1[0]; a1 += (float)v1[1]; a2 += (float)v1[2]; a3 += (float)v1[3]; }
    if (i + 2 < s1) { a0 += (float)v2[0]; a1 += (float)v2[1]; a2 += (float)v2[2]; a3 += (float)v2[3]; }
    if (i + 3 < s1) { a0 += (float)v3[0]; a1 += (float)v3[1]; a2 += (float)v3[2]; a3 += (float)v3[3]; }
  }
  float di = deginv[node];
  h4 o;
  o[0] = (_Float16)(a0 * di); o[1] = (_Float16)(a1 * di);
  o[2] = (_Float16)(a2 * di); o[3] = (_Float16)(a3 * di);
  ((h4*)(agg + (size_t)node * NC))[lane] = o;
}

// ---------------- pooling ----------------
__global__ __launch_bounds__(256) void k_pool1(const _Float16* __restrict__ x,
                                               const int* __restrict__ batch,
                                               unsigned* __restrict__ gkey,
                                               float* __restrict__ gsum,
                                               int* __restrict__ gcnt, int N) {
  int chunk = blockIdx.x * 4 + (threadIdx.x >> 6);
  int lane = threadIdx.x & 63;
  int n0 = chunk * 64;
  if (n0 >= N) return;
  int n1 = min(n0 + 64, N);
  float rmax = -3.4e38f, rsum = 0.f;
  int rcnt = 0, curb = batch[n0];
  for (int n = n0; n < n1; ++n) {
    int b = batch[n];
    if (b != curb) {
      atomicMax(&gkey[curb * 64 + lane], fkey(rmax));
      atomicAdd(&gsum[curb * 64 + lane], rsum);
      if (lane == 0) atomicAdd(&gcnt[curb], rcnt);
      rmax = -3.4e38f; rsum = 0.f; rcnt = 0; curb = b;
    }
    float v = (float)x[(size_t)n * 64 + lane];
    rmax = fmaxf(rmax, v);
    rsum += v;
    rcnt++;
  }
  atomicMax(&gkey[curb * 64 + lane], fkey(rmax));
  atomicAdd(&gsum[curb * 64 + lane], rsum);
  if (lane == 0) atomicAdd(&gcnt[curb], rcnt);
}

__global__ __launch_bounds__(1024) void k_pool2(const unsigned* __restrict__ gkey,
                                                const float* __restrict__ gsum,
                                                const int* __restrict__ gcnt,
                                                const float* __restrict__ post_w,
                                                const float* __restrict__ post_b,
                                                float* __restrict__ out) {
  int b = threadIdx.x >> 6, lane = threadIdx.x & 63;
  float m = funkey(gkey[b * 64 + lane]);
  float s = gsum[b * 64 + lane];
  float c = (float)gcnt[b];
  float g = m + s / fmaxf(c, 1.f);
  float ss = g * g;
#pragma unroll
  for (int off = 1; off < 64; off <<= 1) ss += __shfl_xor(ss, off);
  float gn = g / fmaxf(sqrtf(ss), 1e-30f);
  float contrib = gn * post_w[lane];
#pragma unroll
  for (int off = 1; off < 64; off <<= 1) contrib += __shfl_xor(contrib, off);
  if (lane == 0) out[b] = contrib + post_b[0];
}

extern "C" void kernel_launch(void* const* d_in, const int* in_sizes, int n_in,
                              void* d_out, int out_size, void* d_ws, size_t ws_size,
                              hipStream_t stream) {
  const float* node_feat = (const float*)d_in[0];
  const float* cfgf      = (const float*)d_in[1];
  const int*   opcode    = (const int*)d_in[2];
  const int*   eidx      = (const int*)d_in[3];
  const int*   batch     = (const int*)d_in[4];
  const float* op_emb    = (const float*)d_in[5];
  const float* type_emb  = (const float*)d_in[6];
  const float* lin_w     = (const float*)d_in[7];
  const float* lin_b     = (const float*)d_in[8];
  const float* post_w    = (const float*)d_in[9];
  const float* post_b    = (const float*)d_in[10];
  const float* wp[3] = {(const float*)d_in[11], (const float*)d_in[16], (const float*)d_in[21]};
  const float* bp[3] = {(const float*)d_in[12], (const float*)d_in[17], (const float*)d_in[22]};
  const float* wl[3] = {(const float*)d_in[13], (const float*)d_in[18], (const float*)d_in[23]};
  const float* bl[3] = {(const float*)d_in[14], (const float*)d_in[19], (const float*)d_in[24]};
  const float* wr[3] = {(const float*)d_in[15], (const float*)d_in[20], (const float*)d_in[25]};

  const int N = in_sizes[2];
  const int E = in_sizes[3] / 2;
  const int NPAD = ((N + 255) / 256) * 256;
  const int* e_src = eidx;
  const int* e_dst = eidx + E;

  char* p = (char*)d_ws;
  auto alloc = [&](size_t bytes) -> void* {
    void* r = (void*)p;
    p += (bytes + 255) & ~(size_t)255;
    return r;
  };
  _Float16* X1 = (_Float16*)alloc((size_t)NPAD * 128 * 2);
  _Float16* R2 = (_Float16*)alloc((size_t)NPAD * 128 * 2);
  _Float16* R3 = (_Float16*)alloc((size_t)NPAD * 128 * 2);
  _Float16* WT = (_Float16*)alloc(86016 * 2);
  int* counts    = (int*)alloc((size_t)N * 4);
  int* offsets   = (int*)alloc((size_t)(N + 1) * 4);
  int* fillpos   = (int*)alloc((size_t)N * 4);
  float* deginv  = (float*)alloc((size_t)N * 4);
  int* blockSums = (int*)alloc(1024 * 4);
  int* esrc      = (int*)alloc((size_t)E * 4);
  unsigned* gkey = (unsigned*)alloc(16 * 64 * 4);
  float* gsum    = (float*)alloc(16 * 64 * 4);
  int* gcnt      = (int*)alloc(16 * 4);
  (void)ws_size; (void)n_in; (void)out_size;

  _Float16* WTenc = WT + 0;       // 128 x 224
  _Float16* WTp0  = WT + 28672;   // 128 x 128
  _Float16* WTl0  = WT + 45056;   // 64 x 128
  _Float16* WTr0  = WT + 53248;   // 64 x 128
  _Float16* WTp1  = WT + 61440;   // 64 x 64
  _Float16* WTl1  = WT + 65536;
  _Float16* WTr1  = WT + 69632;
  _Float16* WTp2  = WT + 73728;
  _Float16* WTl2  = WT + 77824;
  _Float16* WTr2  = WT + 81920;

  WDs wds;
  wds.d[0] = {lin_w, WTenc, 193, 128, 224, 0};
  wds.d[1] = {wp[0], WTp0, 128, 128, 128, 28672};
  wds.d[2] = {wl[0], WTl0, 128, 64, 128, 45056};
  wds.d[3] = {wr[0], WTr0, 128, 64, 128, 53248};
  wds.d[4] = {wp[1], WTp1, 64, 64, 64, 61440};
  wds.d[5] = {wl[1], WTl1, 64, 64, 64, 65536};
  wds.d[6] = {wr[1], WTr1, 64, 64, 64, 69632};
  wds.d[7] = {wp[2], WTp2, 64, 64, 64, 73728};
  wds.d[8] = {wl[2], WTl2, 64, 64, 64, 77824};
  wds.d[9] = {wr[2], WTr2, 64, 64, 64, 81920};
  wds.total = 86016;

  hipMemsetAsync(counts, 0, (size_t)N * 4, stream);
  hipMemsetAsync(gkey, 0, 16 * 64 * 4, stream);
  hipMemsetAsync(gsum, 0, 16 * 64 * 4, stream);
  hipMemsetAsync(gcnt, 0, 16 * 4, stream);
  // Zero the never-stored tail rows [N, NPAD) of the activation buffers so every
  // byte any kernel reads is written in-launch -> output is call-invariant under
  // graph replay / workspace re-poisoning (k_mm A-loads cover NPAD rows; stores
  // are guarded r < N). 48 KiB each — negligible.
  if (NPAD > N) {
    const size_t tail = (size_t)(NPAD - N) * 128 * 2;
    hipMemsetAsync(X1 + (size_t)N * 128, 0, tail, stream);
    hipMemsetAsync(R2 + (size_t)N * 128, 0, tail, stream);
    hipMemsetAsync(R3 + (size_t)N * 128, 0, tail, stream);
  }

  const int nbE = (E + 255) / 256;
  const int nbN = (N + 255) / 256;
  const int nbMM = NPAD / 256;
  const int nbMMF = NPAD / 64;
  const int nbA128 = ((size_t)N * 32 + 255) / 256;
  const int nbA64  = ((size_t)N * 16 + 255) / 256;
  const int nbP = ((N + 63) / 64 + 3) / 4;

  k_wconv<<<(86016 + 255) / 256, 256, 0, stream>>>(wds);
  k_count<<<nbE, 256, 0, stream>>>(e_dst, counts, E);
  k_scan1<<<nbN, 256, 0, stream>>>(counts, offsets, blockSums, N);
  k_scan2<<<1, 1024, 0, stream>>>(blockSums, nbN);
  k_scan3<<<nbN, 256, 0, stream>>>(counts, offsets, blockSums, fillpos, deginv, N, E);
  k_fill<<<nbE, 256, 0, stream>>>(e_src, e_dst, fillpos, esrc, E);

  // fused encode: relu(concat @ Wenc + lin_b) -> X1 (N x 128), no F intermediate
  k_mmF<<<nbMMF, 256, 0, stream>>>(node_feat, cfgf, opcode, op_emb, type_emb,
                                   WTenc, lin_b, X1, N);

  // ---- layer 0 ----
  k_mm<128, 0, 128, 0><<<nbMM, 256, 0, stream>>>(X1, WTp0, nullptr, nullptr, bp[0], R2, N);
  k_agg<128><<<nbA128, 256, 0, stream>>>(R2, offsets, esrc, deginv, R3, N);
  k_mm<128, 128, 64, 1><<<nbMM, 256, 0, stream>>>(R3, WTl0, X1, WTr0, bl[0], R2, N);
  // ---- layer 1 ----
  k_mm<64, 0, 64, 0><<<nbMM, 256, 0, stream>>>(R2, WTp1, nullptr, nullptr, bp[1], R3, N);
  k_agg<64><<<nbA64, 256, 0, stream>>>(R3, offsets, esrc, deginv, X1, N);
  k_mm<64, 64, 64, 1><<<nbMM, 256, 0, stream>>>(X1, WTl1, R2, WTr1, bl[1], R3, N);
  // ---- layer 2 ----
  k_mm<64, 0, 64, 0><<<nbMM, 256, 0, stream>>>(R3, WTp2, nullptr, nullptr, bp[2], X1, N);
  k_agg<64><<<nbA64, 256, 0, stream>>>(X1, offsets, esrc, deginv, R2, N);
  k_mm<64, 64, 64, 1><<<nbMM, 256, 0, stream>>>(R2, WTl2, R3, WTr2, bl[2], X1, N);

  // pooling -> out (B=16)
  k_pool1<<<nbP, 256, 0, stream>>>(X1, batch, gkey, gsum, gcnt, N);
  k_pool2<<<1, 1024, 0, stream>>>(gkey, gsum, gcnt, post_w, post_b, (float*)d_out);
}

// Round 9
// 681.396 us; speedup vs baseline: 1.1051x; 1.0103x over previous
//
#include <hip/hip_runtime.h>

typedef _Float16 half8 __attribute__((ext_vector_type(8)));
typedef _Float16 h4 __attribute__((ext_vector_type(4)));
typedef _Float16 h2 __attribute__((ext_vector_type(2)));
typedef float f32x4 __attribute__((ext_vector_type(4)));

__device__ __forceinline__ unsigned fkey(float f) {
  unsigned u = __float_as_uint(f);
  return (u & 0x80000000u) ? ~u : (u | 0x80000000u);
}
__device__ __forceinline__ float funkey(unsigned k) {
  unsigned u = (k & 0x80000000u) ? (k ^ 0x80000000u) : ~k;
  return __uint_as_float(u);
}

__device__ __forceinline__ half8 cvt8(float4 a, float4 b) {
  half8 o;
  o[0] = (_Float16)a.x; o[1] = (_Float16)a.y; o[2] = (_Float16)a.z; o[3] = (_Float16)a.w;
  o[4] = (_Float16)b.x; o[5] = (_Float16)b.y; o[6] = (_Float16)b.z; o[7] = (_Float16)b.w;
  return o;
}

// ---------------- weight convert: fp32 KxNC -> f16 transposed NC x Kpad ----------------
struct WD { const float* src; _Float16* dst; int K, NC, Kpad, base; };
struct WDs { WD d[10]; int total; };

__global__ __launch_bounds__(256) void k_wconv(WDs w) {
  int idx = blockIdx.x * 256 + threadIdx.x;
  if (idx >= w.total) return;
#pragma unroll
  for (int i = 0; i < 10; ++i) {
    int rel = idx - w.d[i].base;
    int sz = w.d[i].NC * w.d[i].Kpad;
    if (rel >= 0 && rel < sz) {
      int n = rel / w.d[i].Kpad;
      int k = rel - n * w.d[i].Kpad;
      w.d[i].dst[rel] = (k < w.d[i].K) ? (_Float16)w.d[i].src[(size_t)k * w.d[i].NC + n]
                                       : (_Float16)0.f;
      return;
    }
  }
}

// ---------------- CSR build ----------------
__global__ __launch_bounds__(256) void k_count(const int* __restrict__ dst,
                                               int* __restrict__ counts, int E) {
  int e = blockIdx.x * 256 + threadIdx.x;
  if (e < E) atomicAdd(&counts[dst[e]], 1);
}

__global__ __launch_bounds__(256) void k_scan1(const int* __restrict__ counts,
                                               int* __restrict__ offsets,
                                               int* __restrict__ blockSums, int N) {
  __shared__ int sm[256];
  int tid = threadIdx.x;
  int gid = blockIdx.x * 256 + tid;
  int v = (gid < N) ? counts[gid] : 0;
  sm[tid] = v;
  __syncthreads();
  for (int off = 1; off < 256; off <<= 1) {
    int t = (tid >= off) ? sm[tid - off] : 0;
    __syncthreads();
    sm[tid] += t;
    __syncthreads();
  }
  if (gid < N) offsets[gid] = sm[tid] - v;
  if (tid == 255) blockSums[blockIdx.x] = sm[255];
}

__global__ __launch_bounds__(1024) void k_scan2(int* __restrict__ blockSums, int NB) {
  __shared__ int sm[1024];
  int tid = threadIdx.x;
  int v = (tid < NB) ? blockSums[tid] : 0;
  sm[tid] = v;
  __syncthreads();
  for (int off = 1; off < 1024; off <<= 1) {
    int t = (tid >= off) ? sm[tid - off] : 0;
    __syncthreads();
    sm[tid] += t;
    __syncthreads();
  }
  if (tid < NB) blockSums[tid] = sm[tid] - v;
}

__global__ __launch_bounds__(256) void k_scan3(const int* __restrict__ counts,
                                               int* __restrict__ offsets,
                                               const int* __restrict__ blockSums,
                                               int* __restrict__ fillpos,
                                               float* __restrict__ deginv, int N, int E) {
  int gid = blockIdx.x * 256 + threadIdx.x;
  if (gid < N) {
    int off = offsets[gid] + blockSums[gid >> 8];
    offsets[gid] = off;
    fillpos[gid] = off;
    deginv[gid] = 1.f / fmaxf((float)counts[gid], 1.f);
  }
  if (gid == 0) offsets[N] = E;
}

__global__ __launch_bounds__(256) void k_fill(const int* __restrict__ src,
                                              const int* __restrict__ dst,
                                              int* __restrict__ fillpos,
                                              int* __restrict__ esrc, int E) {
  int e = blockIdx.x * 256 + threadIdx.x;
  if (e < E) {
    int p = atomicAdd(&fillpos[dst[e]], 1);
    esrc[p] = src[e];
  }
}

// ---------------- fused encode: relu(concat-features @ Wenc + b) -> X1 (N x 128) -------
// RT=1, one row per thread. All A-source loads issued up front (2 dependency layers,
// branchless aligned addresses); A-fragments assembled register-only. B is double-
// buffered in registers: all 8 fragments of step k+1 prefetch while step k's MFMAs run.
// __launch_bounds__(256,2) lifts the VGPR cap (the r7 compiler chose 64 VGPRs for
// occupancy, leaving ~1 load in flight -> 110 serialized latencies ~= the measured
// 62K cyc/wave). Fewer waves with 8-deep load batches beats many starved waves.
// Virtual feature layout (224 cols): 0..138 nf | 139..142 type_emb[nf139] |
// 143..174 op_emb[opcode] | 175..192 cfg | 193..223 zeros.
__global__ __launch_bounds__(256, 2) void k_mmF(
    const float* __restrict__ node_feat, const float* __restrict__ cfgf,
    const int* __restrict__ opcode, const float* __restrict__ op_emb,
    const float* __restrict__ type_emb,
    const _Float16* __restrict__ W0, const float* __restrict__ bias,
    _Float16* __restrict__ Out, int N) {
  constexpr int K0 = 224, NC = 128;
  constexpr int NT = NC / 16;

  const int lane = threadIdx.x & 63, wave = threadIdx.x >> 6;
  const int quad = lane >> 4, l15 = lane & 15;
  const int r0 = blockIdx.x * 64 + wave * 16;
  const int r = min(r0 + l15, N - 1);  // clamp: sources are exactly N rows
  const float* fr = node_feat + (size_t)r * 140;
  const float* cg = cfgf + (size_t)r * 18;

  // ---- layer-0 loads (independent) ----
  int opc = opcode[r];
  float4 f136 = *(const float4*)(fr + 136);            // cols 136..139 (139 = type id)
  float4 fA0 = *(const float4*)(fr + quad * 8 + 0),  fB0 = *(const float4*)(fr + quad * 8 + 4);
  float4 fA1 = *(const float4*)(fr + quad * 8 + 32), fB1 = *(const float4*)(fr + quad * 8 + 36);
  float4 fA2 = *(const float4*)(fr + quad * 8 + 64), fB2 = *(const float4*)(fr + quad * 8 + 68);
  float4 fA3 = *(const float4*)(fr + quad * 8 + 96), fB3 = *(const float4*)(fr + quad * 8 + 100);
  float4 fXa = *(const float4*)(fr + 128),           fXb = *(const float4*)(fr + 132);
  float c17 = cg[17];
  const int cshift = (quad == 3) ? 8 : 0;              // q3 reads cfg[8..17], others cfg[0..9]
  float2 c2a = *(const float2*)(cg + cshift + 0);
  float2 c2b = *(const float2*)(cg + cshift + 2);
  float2 c2c = *(const float2*)(cg + cshift + 4);
  float2 c2d = *(const float2*)(cg + cshift + 6);
  float2 c2e = *(const float2*)(cg + cshift + 8);

  // ---- layer-1 loads (1 dependency hop) ----
  const float* ob = op_emb + opc * 32;
  // per-quad op span starts: q0->17..24, q1->25..31, q2->1..8, q3->9..16 (all = 1 mod 4)
  const int opoff = (quad == 0) ? 17 : (quad == 1) ? 25 : (quad == 2) ? 1 : 9;
  float4 oA = *(const float4*)(ob + opoff - 1);        // aligned slot containing start
  float4 oB = *(const float4*)(ob + opoff + 3);
  float4 oC4 = *(const float4*)(ob + min(opoff + 7, 28));  // clamp keeps q1 in-bounds
  float opC = ob[0];
  int ty = min(max((int)f136.w, 0), 7);
  float4 tyv = *(const float4*)(type_emb + ty * 4);

  // ---- register-only fragment assembly ----
  half8 a0 = cvt8(fA0, fB0), a1 = cvt8(fA1, fB1), a2 = cvt8(fA2, fB2), a3 = cvt8(fA3, fB3);
  half8 opH;  // op_emb[opoff .. opoff+7]
  opH[0] = (_Float16)oA.y; opH[1] = (_Float16)oA.z; opH[2] = (_Float16)oA.w;
  opH[3] = (_Float16)oB.x; opH[4] = (_Float16)oB.y; opH[5] = (_Float16)oB.z;
  opH[6] = (_Float16)oB.w; opH[7] = (_Float16)oC4.x;
  half8 cfH;  // cfg[cshift+1 .. cshift+8]
  cfH[0] = (_Float16)c2a.y; cfH[1] = (_Float16)c2b.x; cfH[2] = (_Float16)c2b.y;
  cfH[3] = (_Float16)c2c.x; cfH[4] = (_Float16)c2c.y; cfH[5] = (_Float16)c2d.x;
  cfH[6] = (_Float16)c2d.y; cfH[7] = (_Float16)c2e.x;
  half8 z8;
#pragma unroll
  for (int j = 0; j < 8; ++j) z8[j] = (_Float16)0.f;

  half8 a4, a5, a6;
  if (quad == 0) {           // k4: cols 128..135 | k5: op 17..24 | k6: cfg17 + zeros
    a4 = cvt8(fXa, fXb);
    a5 = opH;
    a6 = z8; a6[0] = (_Float16)c17;
  } else if (quad == 1) {    // k4: nf136-138|type0-3|op0 | k5: op25-31|cfg0 | k6: zeros
    a4[0] = (_Float16)f136.x; a4[1] = (_Float16)f136.y; a4[2] = (_Float16)f136.z;
    a4[3] = (_Float16)tyv.x;  a4[4] = (_Float16)tyv.y;  a4[5] = (_Float16)tyv.z;
    a4[6] = (_Float16)tyv.w;  a4[7] = (_Float16)opC;
    a5 = opH; a5[7] = (_Float16)c2a.x;
    a6 = z8;
  } else {                   // q2: op1-8 / cfg1-8 ; q3: op9-16 / cfg9-16 ; zeros
    a4 = opH;
    a5 = cfH;
    a6 = z8;
  }

  f32x4 acc[NT];
#pragma unroll
  for (int t = 0; t < NT; ++t) acc[t] = (f32x4)0.f;

  const half8 A[7] = {a0, a1, a2, a3, a4, a5, a6};
  const _Float16* Wb = W0 + (size_t)l15 * K0 + quad * 8;

  // ---- double-buffered B: prefetch step k+1 while step k's MFMAs run ----
  half8 bc[NT], bn[NT];
#pragma unroll
  for (int t = 0; t < NT; ++t) bc[t] = *(const half8*)(Wb + (size_t)t * 16 * K0);
#pragma unroll
  for (int k = 0; k < 7; ++k) {
    if (k < 6) {
#pragma unroll
      for (int t = 0; t < NT; ++t)
        bn[t] = *(const half8*)(Wb + (size_t)t * 16 * K0 + (k + 1) * 32);
    }
#pragma unroll
    for (int t = 0; t < NT; ++t)
      acc[t] = __builtin_amdgcn_mfma_f32_16x16x32_f16(A[k], bc[t], acc[t], 0, 0, 0);
    if (k < 6) {
#pragma unroll
      for (int t = 0; t < NT; ++t) bc[t] = bn[t];
    }
  }

#pragma unroll
  for (int t = 0; t < NT; ++t) {
    float bv = bias[t * 16 + l15];
    acc[t][0] = fmaxf(acc[t][0] + bv, 0.f);
    acc[t][1] = fmaxf(acc[t][1] + bv, 0.f);
    acc[t][2] = fmaxf(acc[t][2] + bv, 0.f);
    acc[t][3] = fmaxf(acc[t][3] + bv, 0.f);
  }
#pragma unroll
  for (int j = 0; j < 4; ++j) {
    int rw = r0 + quad * 4 + j;
    if (rw < N) {
#pragma unroll
      for (int t = 0; t < NT; ++t)
        Out[(size_t)rw * NC + t * 16 + l15] = (_Float16)acc[t][j];
    }
  }
}

// ---------------- MFMA GEMM, B staged in LDS ----------------
// Out[r,:] = epi( A0[r]@W0 (+ A1[r]@W1) + bias ), A f16 row-major pitch K, W f16
// transposed (NC x K). MODE 0 = relu, 1 = row L2-normalize.
// 256 thr = 4 waves; 64 rows/wave (4 row-tiles), 256 rows/block.
template <int K0, int K1, int NC, int MODE>
__global__ __launch_bounds__(256) void k_mm(
    const _Float16* __restrict__ A0, const _Float16* __restrict__ W0,
    const _Float16* __restrict__ A1, const _Float16* __restrict__ W1,
    const float* __restrict__ bias, _Float16* __restrict__ Out, int N) {
  constexpr int NT = NC / 16;  // col tiles
  constexpr int RT = 4;        // row tiles per wave
  constexpr int KP0 = K0 + 8;  // padded LDS pitch (f16)
  constexpr int KP1 = K1 + 8;
  __shared__ _Float16 sB0[NC * KP0];
  __shared__ _Float16 sB1[(K1 > 0) ? (NC * KP1) : 8];

  for (int idx = threadIdx.x; idx < NC * (K0 / 8); idx += 256) {
    int nn = idx / (K0 / 8), k8 = idx - nn * (K0 / 8);
    *(half8*)(sB0 + nn * KP0 + k8 * 8) = *(const half8*)(W0 + (size_t)nn * K0 + k8 * 8);
  }
  if constexpr (K1 > 0) {
    for (int idx = threadIdx.x; idx < NC * (K1 / 8); idx += 256) {
      int nn = idx / (K1 / 8), k8 = idx - nn * (K1 / 8);
      *(half8*)(sB1 + nn * KP1 + k8 * 8) = *(const half8*)(W1 + (size_t)nn * K1 + k8 * 8);
    }
  }
  __syncthreads();

  const int lane = threadIdx.x & 63, wave = threadIdx.x >> 6;
  const int quad = lane >> 4, l15 = lane & 15;
  const int r0 = blockIdx.x * 256 + wave * 64;

  f32x4 acc[RT][NT];
#pragma unroll
  for (int rt = 0; rt < RT; ++rt)
#pragma unroll
    for (int t = 0; t < NT; ++t) acc[rt][t] = (f32x4)0.f;

  {
    const _Float16* ap = A0 + (size_t)(r0 + l15) * K0 + quad * 8;
#pragma unroll
    for (int k = 0; k < K0; k += 32) {
      half8 a[RT];
#pragma unroll
      for (int rt = 0; rt < RT; ++rt) a[rt] = *(const half8*)(ap + (size_t)rt * 16 * K0 + k);
#pragma unroll
      for (int t = 0; t < NT; ++t) {
        half8 b = *(const half8*)(sB0 + (t * 16 + l15) * KP0 + quad * 8 + k);
#pragma unroll
        for (int rt = 0; rt < RT; ++rt)
          acc[rt][t] = __builtin_amdgcn_mfma_f32_16x16x32_f16(a[rt], b, acc[rt][t], 0, 0, 0);
      }
    }
  }
  if constexpr (K1 > 0) {
    const _Float16* ap = A1 + (size_t)(r0 + l15) * K1 + quad * 8;
#pragma unroll
    for (int k = 0; k < K1; k += 32) {
      half8 a[RT];
#pragma unroll
      for (int rt = 0; rt < RT; ++rt) a[rt] = *(const half8*)(ap + (size_t)rt * 16 * K1 + k);
#pragma unroll
      for (int t = 0; t < NT; ++t) {
        half8 b = *(const half8*)(sB1 + (t * 16 + l15) * KP1 + quad * 8 + k);
#pragma unroll
        for (int rt = 0; rt < RT; ++rt)
          acc[rt][t] = __builtin_amdgcn_mfma_f32_16x16x32_f16(a[rt], b, acc[rt][t], 0, 0, 0);
      }
    }
  }

#pragma unroll
  for (int rt = 0; rt < RT; ++rt) {
#pragma unroll
    for (int t = 0; t < NT; ++t) {
      float bv = bias[t * 16 + l15];
      acc[rt][t][0] += bv; acc[rt][t][1] += bv;
      acc[rt][t][2] += bv; acc[rt][t][3] += bv;
    }
    if constexpr (MODE == 1) {
      f32x4 ss = (f32x4)0.f;
#pragma unroll
      for (int t = 0; t < NT; ++t) ss += acc[rt][t] * acc[rt][t];
#pragma unroll
      for (int j = 0; j < 4; ++j) {
        float s = ss[j];
        s += __shfl_xor(s, 1);
        s += __shfl_xor(s, 2);
        s += __shfl_xor(s, 4);
        s += __shfl_xor(s, 8);
        float sc = 1.f / fmaxf(sqrtf(s), 1e-12f);
#pragma unroll
        for (int t = 0; t < NT; ++t) acc[rt][t][j] *= sc;
      }
    } else {
#pragma unroll
      for (int t = 0; t < NT; ++t) {
        acc[rt][t][0] = fmaxf(acc[rt][t][0], 0.f);
        acc[rt][t][1] = fmaxf(acc[rt][t][1], 0.f);
        acc[rt][t][2] = fmaxf(acc[rt][t][2], 0.f);
        acc[rt][t][3] = fmaxf(acc[rt][t][3], 0.f);
      }
    }
#pragma unroll
    for (int j = 0; j < 4; ++j) {
      int r = r0 + rt * 16 + quad * 4 + j;
      if (r < N) {
#pragma unroll
        for (int t = 0; t < NT; ++t)
          Out[(size_t)r * NC + t * 16 + l15] = (_Float16)acc[rt][t][j];
      }
    }
  }
}

// ---------------- CSR mean aggregation (f16, fp32 acc), 8B/lane + 4x edge unroll ----
template <int NC>
__global__ __launch_bounds__(256) void k_agg(const _Float16* __restrict__ xp,
                                             const int* __restrict__ offs,
                                             const int* __restrict__ esrc,
                                             const float* __restrict__ deginv,
                                             _Float16* __restrict__ agg, int N) {
  constexpr int LPN = NC / 4;  // lanes per node, 4 f16 (8B) per lane
  int t = blockIdx.x * 256 + threadIdx.x;
  int node = t / LPN;
  int lane = t - node * LPN;
  if (node >= N) return;
  int s0 = offs[node], s1 = offs[node + 1];
  float a0 = 0.f, a1 = 0.f, a2 = 0.f, a3 = 0.f;
  for (int i = s0; i < s1; i += 4) {
    int nlast = s1 - 1;
    int e0 = esrc[i];
    int e1 = esrc[min(i + 1, nlast)];
    int e2 = esrc[min(i + 2, nlast)];
    int e3 = esrc[min(i + 3, nlast)];
    h4 v0 = ((const h4*)(xp + (size_t)e0 * NC))[lane];
    h4 v1 = ((const h4*)(xp + (size_t)e1 * NC))[lane];
    h4 v2 = ((const h4*)(xp + (size_t)e2 * NC))[lane];
    h4 v3 = ((const h4*)(xp + (size_t)e3 * NC))[lane];
    a0 += (float)v0[0]; a1 += (float)v0[1]; a2 += (float)v0[2]; a3 += (float)v0[3];
    if (i + 1 < s1) { a0 += (float)v1[0]; a1 += (float)v1[1]; a2 += (float)v1[2]; a3 += (float)v1[3]; }
    if (i + 2 < s1) { a0 += (float)v2[0]; a1 += (float)v2[1]; a2 += (float)v2[2]; a3 += (float)v2[3]; }
    if (i + 3 < s1) { a0 += (float)v3[0]; a1 += (float)v3[1]; a2 += (float)v3[2]; a3 += (float)v3[3]; }
  }
  float di = deginv[node];
  h4 o;
  o[0] = (_Float16)(a0 * di); o[1] = (_Float16)(a1 * di);
  o[2] = (_Float16)(a2 * di); o[3] = (_Float16)(a3 * di);
  ((h4*)(agg + (size_t)node * NC))[lane] = o;
}

// ---------------- pooling ----------------
__global__ __launch_bounds__(256) void k_pool1(const _Float16* __restrict__ x,
                                               const int* __restrict__ batch,
                                               unsigned* __restrict__ gkey,
                                               float* __restrict__ gsum,
                                               int* __restrict__ gcnt, int N) {
  int chunk = blockIdx.x * 4 + (threadIdx.x >> 6);
  int lane = threadIdx.x & 63;
  int n0 = chunk * 64;
  if (n0 >= N) return;
  int n1 = min(n0 + 64, N);
  float rmax = -3.4e38f, rsum = 0.f;
  int rcnt = 0, curb = batch[n0];
  for (int n = n0; n < n1; ++n) {
    int b = batch[n];
    if (b != curb) {
      atomicMax(&gkey[curb * 64 + lane], fkey(rmax));
      atomicAdd(&gsum[curb * 64 + lane], rsum);
      if (lane == 0) atomicAdd(&gcnt[curb], rcnt);
      rmax = -3.4e38f; rsum = 0.f; rcnt = 0; curb = b;
    }
    float v = (float)x[(size_t)n * 64 + lane];
    rmax = fmaxf(rmax, v);
    rsum += v;
    rcnt++;
  }
  atomicMax(&gkey[curb * 64 + lane], fkey(rmax));
  atomicAdd(&gsum[curb * 64 + lane], rsum);
  if (lane == 0) atomicAdd(&gcnt[curb], rcnt);
}

__global__ __launch_bounds__(1024) void k_pool2(const unsigned* __restrict__ gkey,
                                                const float* __restrict__ gsum,
                                                const int* __restrict__ gcnt,
                                                const float* __restrict__ post_w,
                                                const float* __restrict__ post_b,
                                                float* __restrict__ out) {
  int b = threadIdx.x >> 6, lane = threadIdx.x & 63;
  float m = funkey(gkey[b * 64 + lane]);
  float s = gsum[b * 64 + lane];
  float c = (float)gcnt[b];
  float g = m + s / fmaxf(c, 1.f);
  float ss = g * g;
#pragma unroll
  for (int off = 1; off < 64; off <<= 1) ss += __shfl_xor(ss, off);
  float gn = g / fmaxf(sqrtf(ss), 1e-30f);
  float contrib = gn * post_w[lane];
#pragma unroll
  for (int off = 1; off < 64; off <<= 1) contrib += __shfl_xor(contrib, off);
  if (lane == 0) out[b] = contrib + post_b[0];
}

extern "C" void kernel_launch(void* const* d_in, const int* in_sizes, int n_in,
                              void* d_out, int out_size, void* d_ws, size_t ws_size,
                              hipStream_t stream) {
  const float* node_feat = (const float*)d_in[0];
  const float* cfgf      = (const float*)d_in[1];
  const int*   opcode    = (const int*)d_in[2];
  const int*   eidx      = (const int*)d_in[3];
  const int*   batch     = (const int*)d_in[4];
  const float* op_emb    = (const float*)d_in[5];
  const float* type_emb  = (const float*)d_in[6];
  const float* lin_w     = (const float*)d_in[7];
  const float* lin_b     = (const float*)d_in[8];
  const float* post_w    = (const float*)d_in[9];
  const float* post_b    = (const float*)d_in[10];
  const float* wp[3] = {(const float*)d_in[11], (const float*)d_in[16], (const float*)d_in[21]};
  const float* bp[3] = {(const float*)d_in[12], (const float*)d_in[17], (const float*)d_in[22]};
  const float* wl[3] = {(const float*)d_in[13], (const float*)d_in[18], (const float*)d_in[23]};
  const float* bl[3] = {(const float*)d_in[14], (const float*)d_in[19], (const float*)d_in[24]};
  const float* wr[3] = {(const float*)d_in[15], (const float*)d_in[20], (const float*)d_in[25]};

  const int N = in_sizes[2];
  const int E = in_sizes[3] / 2;
  const int NPAD = ((N + 255) / 256) * 256;
  const int* e_src = eidx;
  const int* e_dst = eidx + E;

  char* p = (char*)d_ws;
  auto alloc = [&](size_t bytes) -> void* {
    void* r = (void*)p;
    p += (bytes + 255) & ~(size_t)255;
    return r;
  };
  _Float16* X1 = (_Float16*)alloc((size_t)NPAD * 128 * 2);
  _Float16* R2 = (_Float16*)alloc((size_t)NPAD * 128 * 2);
  _Float16* R3 = (_Float16*)alloc((size_t)NPAD * 128 * 2);
  _Float16* WT = (_Float16*)alloc(86016 * 2);
  int* counts    = (int*)alloc((size_t)N * 4);
  int* offsets   = (int*)alloc((size_t)(N + 1) * 4);
  int* fillpos   = (int*)alloc((size_t)N * 4);
  float* deginv  = (float*)alloc((size_t)N * 4);
  int* blockSums = (int*)alloc(1024 * 4);
  int* esrc      = (int*)alloc((size_t)E * 4);
  unsigned* gkey = (unsigned*)alloc(16 * 64 * 4);
  float* gsum    = (float*)alloc(16 * 64 * 4);
  int* gcnt      = (int*)alloc(16 * 4);
  (void)ws_size; (void)n_in; (void)out_size;

  _Float16* WTenc = WT + 0;       // 128 x 224
  _Float16* WTp0  = WT + 28672;   // 128 x 128
  _Float16* WTl0  = WT + 45056;   // 64 x 128
  _Float16* WTr0  = WT + 53248;   // 64 x 128
  _Float16* WTp1  = WT + 61440;   // 64 x 64
  _Float16* WTl1  = WT + 65536;
  _Float16* WTr1  = WT + 69632;
  _Float16* WTp2  = WT + 73728;
  _Float16* WTl2  = WT + 77824;
  _Float16* WTr2  = WT + 81920;

  WDs wds;
  wds.d[0] = {lin_w, WTenc, 193, 128, 224, 0};
  wds.d[1] = {wp[0], WTp0, 128, 128, 128, 28672};
  wds.d[2] = {wl[0], WTl0, 128, 64, 128, 45056};
  wds.d[3] = {wr[0], WTr0, 128, 64, 128, 53248};
  wds.d[4] = {wp[1], WTp1, 64, 64, 64, 61440};
  wds.d[5] = {wl[1], WTl1, 64, 64, 64, 65536};
  wds.d[6] = {wr[1], WTr1, 64, 64, 64, 69632};
  wds.d[7] = {wp[2], WTp2, 64, 64, 64, 73728};
  wds.d[8] = {wl[2], WTl2, 64, 64, 64, 77824};
  wds.d[9] = {wr[2], WTr2, 64, 64, 64, 81920};
  wds.total = 86016;

  hipMemsetAsync(counts, 0, (size_t)N * 4, stream);
  hipMemsetAsync(gkey, 0, 16 * 64 * 4, stream);
  hipMemsetAsync(gsum, 0, 16 * 64 * 4, stream);
  hipMemsetAsync(gcnt, 0, 16 * 4, stream);
  // Zero the never-stored tail rows [N, NPAD) of the activation buffers so every
  // byte any kernel reads is written in-launch -> output is call-invariant under
  // graph replay / workspace re-poisoning (k_mm A-loads cover NPAD rows; stores
  // are guarded r < N). 48 KiB each — negligible.
  if (NPAD > N) {
    const size_t tail = (size_t)(NPAD - N) * 128 * 2;
    hipMemsetAsync(X1 + (size_t)N * 128, 0, tail, stream);
    hipMemsetAsync(R2 + (size_t)N * 128, 0, tail, stream);
    hipMemsetAsync(R3 + (size_t)N * 128, 0, tail, stream);
  }

  const int nbE = (E + 255) / 256;
  const int nbN = (N + 255) / 256;
  const int nbMM = NPAD / 256;
  const int nbMMF = NPAD / 64;
  const int nbA128 = ((size_t)N * 32 + 255) / 256;
  const int nbA64  = ((size_t)N * 16 + 255) / 256;
  const int nbP = ((N + 63) / 64 + 3) / 4;

  k_wconv<<<(86016 + 255) / 256, 256, 0, stream>>>(wds);
  k_count<<<nbE, 256, 0, stream>>>(e_dst, counts, E);
  k_scan1<<<nbN, 256, 0, stream>>>(counts, offsets, blockSums, N);
  k_scan2<<<1, 1024, 0, stream>>>(blockSums, nbN);
  k_scan3<<<nbN, 256, 0, stream>>>(counts, offsets, blockSums, fillpos, deginv, N, E);
  k_fill<<<nbE, 256, 0, stream>>>(e_src, e_dst, fillpos, esrc, E);

  // fused encode: relu(concat @ Wenc + lin_b) -> X1 (N x 128), no F intermediate
  k_mmF<<<nbMMF, 256, 0, stream>>>(node_feat, cfgf, opcode, op_emb, type_emb,
                                   WTenc, lin_b, X1, N);

  // ---- layer 0 ----
  k_mm<128, 0, 128, 0><<<nbMM, 256, 0, stream>>>(X1, WTp0, nullptr, nullptr, bp[0], R2, N);
  k_agg<128><<<nbA128, 256, 0, stream>>>(R2, offsets, esrc, deginv, R3, N);
  k_mm<128, 128, 64, 1><<<nbMM, 256, 0, stream>>>(R3, WTl0, X1, WTr0, bl[0], R2, N);
  // ---- layer 1 ----
  k_mm<64, 0, 64, 0><<<nbMM, 256, 0, stream>>>(R2, WTp1, nullptr, nullptr, bp[1], R3, N);
  k_agg<64><<<nbA64, 256, 0, stream>>>(R3, offsets, esrc, deginv, X1, N);
  k_mm<64, 64, 64, 1><<<nbMM, 256, 0, stream>>>(X1, WTl1, R2, WTr1, bl[1], R3, N);
  // ---- layer 2 ----
  k_mm<64, 0, 64, 0><<<nbMM, 256, 0, stream>>>(R3, WTp2, nullptr, nullptr, bp[2], X1, N);
  k_agg<64><<<nbA64, 256, 0, stream>>>(X1, offsets, esrc, deginv, R2, N);
  k_mm<64, 64, 64, 1><<<nbMM, 256, 0, stream>>>(R2, WTl2, R3, WTr2, bl[2], X1, N);

  // pooling -> out (B=16)
  k_pool1<<<nbP, 256, 0, stream>>>(X1, batch, gkey, gsum, gcnt, N);
  k_pool2<<<1, 1024, 0, stream>>>(gkey, gsum, gcnt, post_w, post_b, (float*)d_out);
}